// Round 13
// baseline (45.013 us; speedup 1.0000x reference)
//
#include <hip/hip_runtime.h>
#include <hip/hip_bf16.h>
#include <math.h>

// out[i,j] = max( (x[i]·W[j]) / (|x_i| |W_j|), 1e-10 ) + b[j]
// B=65536, IN=OUT=256, fp32 in/out.
// Round 13: K-SPLIT W staging -> 64KB LDS -> 2 INDEPENDENT blocks per CU.
// 512 blocks x 512 thr (8 waves x 16 rows). Phase A: stage W[:,0:128] bf16,
// accumulate all 16 windows over k<128 (acc[i] persists). Restage W[:,128:256]
// into the same buffer. Phase B: re-walk windows, add k>=128, scale+streamed
// stores. Co-resident blocks are unsynchronized -> one drains x / stores while
// the other computes: the CU-level phase decoupling R10-R12 lacked.
// Traffic invariants kept: x read once (x-first order), full out rows/wave,
// W re-read comes from XCD L2 (W is 256KB, L2-hot).

using bf16x8 = __attribute__((ext_vector_type(8))) short;   // 8 bf16 = 4 VGPRs
using f32x4  = __attribute__((ext_vector_type(4))) float;

#define W_LDS_BYTES 65536                         // 256 rows * 256 B (bf16 K-half)
#define LDS_BYTES   (W_LDS_BYTES + 1024 + 1024)   // + winv[256] + b[256]
#define EPS 1e-10f

__device__ __forceinline__ short f2bf(float f) {
    __bf16 h = (__bf16)f;                         // RNE; pairs fuse to v_cvt_pk_bf16_f32
    return __builtin_bit_cast(short, h);
}

__global__ __launch_bounds__(512, 4) void ffn_cosnorm_kernel(
    const float* __restrict__ x, const float* __restrict__ W,
    const float* __restrict__ b, float* __restrict__ out)
{
    extern __shared__ char smem[];
    float* winv = (float*)(smem + W_LDS_BYTES);           // [256] partial ss -> 1/|W_j|
    float* blds = (float*)(smem + W_LDS_BYTES + 1024);    // [256] bias

    const int t    = threadIdx.x;
    const int lane = t & 63;
    const int wave = t >> 6;                  // 0..7
    const int r16  = lane & 15;               // x row within M-tile (= D col, in-lane)
    const int kg   = lane >> 4;               // 0..3 : K-slice of 8
    const int rxor = (r16 & 7) << 4;          // W-frag read swizzle
    const size_t rowb = (size_t)blockIdx.x * 128 + (size_t)wave * 16;

    const float* xp = x + (rowb + r16) * 256 + kg * 8;

    // ---- x burst FIRST (x-first program order = the traffic optimum) ----
    float4 fa[8], fb[8];
    #pragma unroll
    for (int s = 0; s < 8; ++s) {
        fa[s] = *(const float4*)(xp + s * 32);
        fb[s] = *(const float4*)(xp + s * 32 + 4);
    }

    // ---- stage W K-half 0 (cols 0..127) as bf16, swizzled; partial w sumsq ----
    {
        const int wrow = t >> 1;              // 0..255 W row (output col j)
        const int q    = t & 1;               // which 64-col quarter of this half
        const float* wr = W + (size_t)wrow * 256 + q * 64;
        const int rx = (wrow & 7) << 4;
        float ss = 0.f;
        #pragma unroll
        for (int i = 0; i < 8; ++i) {         // 8 groups of 8 floats
            float4 a = *(const float4*)(wr + i * 8);
            float4 c = *(const float4*)(wr + i * 8 + 4);
            ss = fmaf(a.x, a.x, ss); ss = fmaf(a.y, a.y, ss);
            ss = fmaf(a.z, a.z, ss); ss = fmaf(a.w, a.w, ss);
            ss = fmaf(c.x, c.x, ss); ss = fmaf(c.y, c.y, ss);
            ss = fmaf(c.z, c.z, ss); ss = fmaf(c.w, c.w, ss);
            bf16x8 v;
            v[0] = f2bf(a.x); v[1] = f2bf(a.y); v[2] = f2bf(a.z); v[3] = f2bf(a.w);
            v[4] = f2bf(c.x); v[5] = f2bf(c.y); v[6] = f2bf(c.z); v[7] = f2bf(c.w);
            const int off = wrow * 256 + ((q * 128 + i * 16) ^ rx);
            *(bf16x8*)(smem + off) = v;       // ds_write_b128
        }
        ss += __shfl_xor(ss, 1);              // combine the 2 quarters
        if (!q) winv[wrow] = ss;              // raw partial (finalized in half 1)
        else    blds[wrow] = b[wrow];
    }

    // ---- convert x -> bf16 fragments + fp32 sum-of-squares ----
    bf16x8 xb[8];                             // 32 VGPR persistent
    float ssx = 0.f;
    #pragma unroll
    for (int s = 0; s < 8; ++s) {
        float4 a = fa[s], c = fb[s];
        bf16x8 v;
        v[0] = f2bf(a.x); v[1] = f2bf(a.y); v[2] = f2bf(a.z); v[3] = f2bf(a.w);
        v[4] = f2bf(c.x); v[5] = f2bf(c.y); v[6] = f2bf(c.z); v[7] = f2bf(c.w);
        xb[s] = v;
        ssx = fmaf(a.x, a.x, ssx); ssx = fmaf(a.y, a.y, ssx);
        ssx = fmaf(a.z, a.z, ssx); ssx = fmaf(a.w, a.w, ssx);
        ssx = fmaf(c.x, c.x, ssx); ssx = fmaf(c.y, c.y, ssx);
        ssx = fmaf(c.z, c.z, ssx); ssx = fmaf(c.w, c.w, ssx);
    }
    ssx += __shfl_xor(ssx, 16); ssx += __shfl_xor(ssx, 32);
    const float inv = 1.0f / sqrtf(ssx);      // 1/|x_row(r16)|

    __syncthreads();                          // barrier 1: W half-0 staged

    // ---------------- phase A: accumulate k = 0..127 for 16 windows ----------------
    f32x4 acc[16];                            // 64 VGPR; indexed by i (static), not n
    #pragma unroll
    for (int i = 0; i < 16; ++i) {
        const int n = (wave * 2 + i) & 15;    // wave-rotated window order
        f32x4 a = f32x4{0.f, 0.f, 0.f, 0.f};
        #pragma unroll
        for (int k0 = 0; k0 < 4; ++k0) {      // 4 K-steps of 32 (this half)
            const int addr = (n * 16 + r16) * 256 + ((k0 * 64 + kg * 16) ^ rxor);
            bf16x8 wfr = *(const bf16x8*)(smem + addr);   // ds_read_b128
            a = __builtin_amdgcn_mfma_f32_16x16x32_bf16(wfr, xb[k0], a, 0, 0, 0);
        }
        acc[i] = a;
    }

    __syncthreads();                          // barrier 2: all half-0 reads done

    // ---- restage: W K-half 1 (cols 128..255) into the same buffer ----
    {
        const int wrow = t >> 1;
        const int q    = t & 1;
        const float* wr = W + (size_t)wrow * 256 + 128 + q * 64;
        const int rx = (wrow & 7) << 4;
        float ss = 0.f;
        #pragma unroll
        for (int i = 0; i < 8; ++i) {
            float4 a = *(const float4*)(wr + i * 8);
            float4 c = *(const float4*)(wr + i * 8 + 4);
            ss = fmaf(a.x, a.x, ss); ss = fmaf(a.y, a.y, ss);
            ss = fmaf(a.z, a.z, ss); ss = fmaf(a.w, a.w, ss);
            ss = fmaf(c.x, c.x, ss); ss = fmaf(c.y, c.y, ss);
            ss = fmaf(c.z, c.z, ss); ss = fmaf(c.w, c.w, ss);
            bf16x8 v;
            v[0] = f2bf(a.x); v[1] = f2bf(a.y); v[2] = f2bf(a.z); v[3] = f2bf(a.w);
            v[4] = f2bf(c.x); v[5] = f2bf(c.y); v[6] = f2bf(c.z); v[7] = f2bf(c.w);
            const int off = wrow * 256 + ((q * 128 + i * 16) ^ rx);
            *(bf16x8*)(smem + off) = v;
        }
        ss += __shfl_xor(ss, 1);
        if (!q) winv[wrow] = 1.0f / sqrtf(winv[wrow] + ss);   // finalize 1/|W_j|
    }

    __syncthreads();                          // barrier 3: W half-1 staged

    // ---------------- phase B: add k = 128..255, scale, clamp, +bias, store ----------------
    const int jb = kg * 4;
    float* op = out + (rowb + r16) * 256;
    #pragma unroll
    for (int i = 0; i < 16; ++i) {
        const int n = (wave * 2 + i) & 15;    // same order as phase A
        f32x4 a = acc[i];
        #pragma unroll
        for (int k0 = 0; k0 < 4; ++k0) {
            const int addr = (n * 16 + r16) * 256 + ((k0 * 64 + kg * 16) ^ rxor);
            bf16x8 wfr = *(const bf16x8*)(smem + addr);   // ds_read_b128
            a = __builtin_amdgcn_mfma_f32_16x16x32_bf16(wfr, xb[4 + k0], a, 0, 0, 0);
        }
        float4 wv = *(const float4*)(winv + n * 16 + jb);
        float4 bv = *(const float4*)(blds + n * 16 + jb);
        f32x4 o;
        o[0] = fmaxf(a[0] * (inv * wv.x), EPS) + bv.x;
        o[1] = fmaxf(a[1] * (inv * wv.y), EPS) + bv.y;
        o[2] = fmaxf(a[2] * (inv * wv.z), EPS) + bv.z;
        o[3] = fmaxf(a[3] * (inv * wv.w), EPS) + bv.w;
        *(f32x4*)(op + n * 16 + jb) = o;      // stores stream through phase B
        __builtin_amdgcn_sched_barrier(0);    // pin per-window interleave
    }
}

extern "C" void kernel_launch(void* const* d_in, const int* in_sizes, int n_in,
                              void* d_out, int out_size, void* d_ws, size_t ws_size,
                              hipStream_t stream) {
    const float* x = (const float*)d_in[0];
    const float* W = (const float*)d_in[1];
    const float* b = (const float*)d_in[2];
    float* out = (float*)d_out;

    hipFuncSetAttribute((const void*)ffn_cosnorm_kernel,
                        hipFuncAttributeMaxDynamicSharedMemorySize, LDS_BYTES);
    ffn_cosnorm_kernel<<<dim3(512), dim3(512), LDS_BYTES, stream>>>(x, W, b, out);
}

// Round 14
// 34.642 us; speedup vs baseline: 1.2994x; 1.2994x over previous
//
#include <hip/hip_runtime.h>
#include <hip/hip_bf16.h>
#include <math.h>

// out[i,j] = max( (x[i]·W[j]) / (|x_i| |W_j|), 1e-10 ) + b[j]
// B=65536, IN=OUT=256, fp32 in/out.
// Round 14: R11 (best, 34.6us: 1024 thr, 16 waves x 16 rows, full W bf16 LDS,
// x-first burst, n-outer streamed stores) with two fixes:
//  (a) NO per-window sched_barrier -> compiler pipelines window n+1 ds_reads
//      under window n MFMAs (store-sinking would need ~64 live VGPRs; won't).
//  (b) W prologue staged by waves 0-7 only, in the proven low-conflict
//      2-threads-per-row layout (R6: 1.31M conflict-cyc vs R11's 2.88M);
//      waves 8-15 go straight to x conversion (staging off their path).

using bf16x8 = __attribute__((ext_vector_type(8))) short;   // 8 bf16 = 4 VGPRs
using f32x4  = __attribute__((ext_vector_type(4))) float;

#define W_LDS_BYTES 131072                        // 256 rows * 512 B (bf16, swizzled)
#define LDS_BYTES   (W_LDS_BYTES + 1024 + 1024)   // + winv[256] + b[256]
#define EPS 1e-10f

__device__ __forceinline__ short f2bf(float f) {
    __bf16 h = (__bf16)f;                         // RNE; pairs fuse to v_cvt_pk_bf16_f32
    return __builtin_bit_cast(short, h);
}

__global__ __launch_bounds__(1024, 4) void ffn_cosnorm_kernel(
    const float* __restrict__ x, const float* __restrict__ W,
    const float* __restrict__ b, float* __restrict__ out)
{
    extern __shared__ char smem[];
    float* winv = (float*)(smem + W_LDS_BYTES);           // [256] 1/|W_j|
    float* blds = (float*)(smem + W_LDS_BYTES + 1024);    // [256] bias

    const int t    = threadIdx.x;
    const int lane = t & 63;
    const int wave = t >> 6;                  // 0..15
    const int r16  = lane & 15;               // x row within M-tile (= D col, in-lane)
    const int kg   = lane >> 4;               // 0..3 : K-slice of 8
    const int rxor = (r16 & 7) << 4;          // W-frag read swizzle
    const size_t rowb = (size_t)blockIdx.x * 256 + (size_t)wave * 16;

    const float* xp = x + (rowb + r16) * 256 + kg * 8;

    // ---- x burst FIRST (x-first program order = the traffic optimum) ----
    float4 fa[8], fb[8];
    #pragma unroll
    for (int s = 0; s < 8; ++s) {
        fa[s] = *(const float4*)(xp + s * 32);
        fb[s] = *(const float4*)(xp + s * 32 + 4);
    }

    // ---- W prologue: waves 0-7 only, 2 threads/row (low-conflict R6 layout) ----
    if (wave < 8) {
        const int wrow = t >> 1;              // 0..255 (W row = output col j)
        const int half = t & 1;               // which 128-col half
        const float* wr = W + (size_t)wrow * 256 + half * 128;
        const int rx = (wrow & 7) << 4;       // swizzle term
        float ss = 0.f;
        #pragma unroll
        for (int i = 0; i < 16; ++i) {        // 16 groups of 8 floats
            float4 a = *(const float4*)(wr + i * 8);
            float4 c = *(const float4*)(wr + i * 8 + 4);
            ss = fmaf(a.x, a.x, ss); ss = fmaf(a.y, a.y, ss);
            ss = fmaf(a.z, a.z, ss); ss = fmaf(a.w, a.w, ss);
            ss = fmaf(c.x, c.x, ss); ss = fmaf(c.y, c.y, ss);
            ss = fmaf(c.z, c.z, ss); ss = fmaf(c.w, c.w, ss);
            bf16x8 v;
            v[0] = f2bf(a.x); v[1] = f2bf(a.y); v[2] = f2bf(a.z); v[3] = f2bf(a.w);
            v[4] = f2bf(c.x); v[5] = f2bf(c.y); v[6] = f2bf(c.z); v[7] = f2bf(c.w);
            const int off = wrow * 512 + ((half * 256 + i * 16) ^ rx);
            *(bf16x8*)(smem + off) = v;       // ds_write_b128
        }
        ss += __shfl_xor(ss, 1);              // combine the two halves
        if (!half) winv[wrow] = 1.0f / sqrtf(ss);
        if (t < 256) blds[t] = b[t];
    }

    // ---- convert x -> bf16 fragments + fp32 sum-of-squares ----
    bf16x8 xb[8];                             // 32 VGPR persistent
    float ssx = 0.f;
    #pragma unroll
    for (int s = 0; s < 8; ++s) {
        float4 a = fa[s], c = fb[s];
        bf16x8 v;
        v[0] = f2bf(a.x); v[1] = f2bf(a.y); v[2] = f2bf(a.z); v[3] = f2bf(a.w);
        v[4] = f2bf(c.x); v[5] = f2bf(c.y); v[6] = f2bf(c.z); v[7] = f2bf(c.w);
        xb[s] = v;
        ssx = fmaf(a.x, a.x, ssx); ssx = fmaf(a.y, a.y, ssx);
        ssx = fmaf(a.z, a.z, ssx); ssx = fmaf(a.w, a.w, ssx);
        ssx = fmaf(c.x, c.x, ssx); ssx = fmaf(c.y, c.y, ssx);
        ssx = fmaf(c.z, c.z, ssx); ssx = fmaf(c.w, c.w, ssx);
    }

    // ---- x_len: butterfly over K-groups; in-lane result ----
    ssx += __shfl_xor(ssx, 16); ssx += __shfl_xor(ssx, 32);
    const float inv = 1.0f / sqrtf(ssx);      // 1/|x_row(r16)|

    __syncthreads();                          // W staged; only barrier in the kernel

    // ---------------- n-outer loop: compute one 16-col window, store, repeat ----
    // No sched_barrier: let the compiler pipeline window n+1's ds_reads under
    // window n's MFMA chain. WRITE_SIZE adjudicates store-sinking.
    const int jb = kg * 4;
    float* op = out + (rowb + r16) * 256;

    #pragma unroll
    for (int n = 0; n < 16; ++n) {
        f32x4 acc = f32x4{0.f, 0.f, 0.f, 0.f};
        #pragma unroll
        for (int k0 = 0; k0 < 8; ++k0) {
            const int addr = (n * 16 + r16) * 512 + ((k0 * 64 + kg * 16) ^ rxor);
            bf16x8 wfr = *(const bf16x8*)(smem + addr);   // ds_read_b128
            acc = __builtin_amdgcn_mfma_f32_16x16x32_bf16(wfr, xb[k0], acc, 0, 0, 0);
        }
        float4 wv = *(const float4*)(winv + n * 16 + jb);
        float4 bv = *(const float4*)(blds + n * 16 + jb);
        f32x4 o;
        o[0] = fmaxf(acc[0] * (inv * wv.x), EPS) + bv.x;
        o[1] = fmaxf(acc[1] * (inv * wv.y), EPS) + bv.y;
        o[2] = fmaxf(acc[2] * (inv * wv.z), EPS) + bv.z;
        o[3] = fmaxf(acc[3] * (inv * wv.w), EPS) + bv.w;
        *(f32x4*)(op + n * 16 + jb) = o;      // stores stream through compute
    }
}

extern "C" void kernel_launch(void* const* d_in, const int* in_sizes, int n_in,
                              void* d_out, int out_size, void* d_ws, size_t ws_size,
                              hipStream_t stream) {
    const float* x = (const float*)d_in[0];
    const float* W = (const float*)d_in[1];
    const float* b = (const float*)d_in[2];
    float* out = (float*)d_out;

    hipFuncSetAttribute((const void*)ffn_cosnorm_kernel,
                        hipFuncAttributeMaxDynamicSharedMemorySize, LDS_BYTES);
    ffn_cosnorm_kernel<<<dim3(256), dim3(1024), LDS_BYTES, stream>>>(x, W, b, out);
}